// Round 2
// baseline (58.620 us; speedup 1.0000x reference)
//
#include <hip/hip_runtime.h>
#include <hip/hip_bf16.h>
#include <math.h>

#define B_DIM 64
#define D_DIM 256
#define C_DIM 100000
#define P_DIM 8
#define N_DIM 32
#define NTILE 3125      // C_DIM / 32
#define RS_SEG 8        // rowsum segments per batch row
#define RS_LEN 12500    // C_DIM / RS_SEG

typedef __attribute__((ext_vector_type(8))) short bf16x8;
typedef __attribute__((ext_vector_type(16))) float f32x16;

__device__ __forceinline__ unsigned short bf16_rn(float f) {
    unsigned int u = __float_as_uint(f);
    unsigned int r = (u + 0x7FFFu + ((u >> 16) & 1u)) >> 16;
    return (unsigned short)r;
}

// Truncate-split: x = hi + lo (hi exact truncation, lo rounds; combined ~2^-17 rel err)
__device__ __forceinline__ void split_bf16(float x, unsigned short& hi, unsigned short& lo) {
    unsigned int bx = __float_as_uint(x);
    unsigned int hb = bx & 0xFFFF0000u;
    hi = (unsigned short)(hb >> 16);
    lo = bf16_rn(x - __uint_as_float(hb));
}

__device__ __forceinline__ float softplusf(float x) { return log1pf(expf(x)); }

// ---------------- Kernel A: norms, sim = ni@ni^T (hi+lo MFMA), hp/hn losses, A-frag precompute ----------------
__global__ __launch_bounds__(256)
void prep_kernel(const float* __restrict__ X,
                 const int* __restrict__ pos_idx, const int* __restrict__ pos_mask,
                 const int* __restrict__ neg_idx, const int* __restrict__ neg_mask,
                 float* __restrict__ wsH, unsigned short* __restrict__ wsA) {
    __shared__ unsigned short fHi[2048 * 8];   // 32 KB: ni hi fragments (frag order)
    __shared__ unsigned short fLo[2048 * 8];   // 32 KB
    __shared__ float sim[64][64];              // 16 KB
    __shared__ float inv[64];
    __shared__ float hp[64];
    __shared__ float contrib[64];
    const int tid = threadIdx.x;
    // row norms: 4 threads per row
    {
        int r = tid >> 2, q = tid & 3;
        const float* row = X + r * D_DIM + q * 64;
        float s = 0.0f;
        #pragma unroll
        for (int i = 0; i < 64; i += 4) {
            float4 v = *(const float4*)(row + i);
            s += v.x * v.x + v.y * v.y + v.z * v.z + v.w * v.w;
        }
        s += __shfl_xor(s, 1);
        s += __shfl_xor(s, 2);
        if (q == 0) inv[r] = 1.0f / fmaxf(sqrtf(s), 1e-12f);
    }
    __syncthreads();
    // fragments: lane l holds M[mt*32+(l&31)][ks*16+8*(l>>5)+j]
    for (int t = tid; t < 2048; t += 256) {
        int l = t & 63, ks = (t >> 6) & 15, mt = t >> 10;
        int row = mt * 32 + (l & 31);
        int col0 = ks * 16 + 8 * (l >> 5);
        const float* src = X + row * D_DIM + col0;
        float iv = inv[row];
        #pragma unroll
        for (int j = 0; j < 8; ++j) {
            unsigned short h, lo;
            split_bf16(src[j] * iv, h, lo);
            fHi[t * 8 + j] = h;
            fLo[t * 8 + j] = lo;
            wsA[t * 8 + j] = bf16_rn(src[j]);   // raw-X hi fragment for logits kernel
        }
    }
    __syncthreads();
    // sim via 4 wave tiles of 32x32 (A-frag and B-frag layouts coincide for ni@ni^T)
    {
        int w = tid >> 6, l = tid & 63;
        int mt = w >> 1, nt = w & 1;
        f32x16 acc;
        #pragma unroll
        for (int i = 0; i < 16; ++i) acc[i] = 0.0f;
        #pragma unroll
        for (int ks = 0; ks < 16; ++ks) {
            const bf16x8 ah = *(const bf16x8*)&fHi[((mt * 16 + ks) * 64 + l) * 8];
            const bf16x8 al = *(const bf16x8*)&fLo[((mt * 16 + ks) * 64 + l) * 8];
            const bf16x8 bh = *(const bf16x8*)&fHi[((nt * 16 + ks) * 64 + l) * 8];
            const bf16x8 bl = *(const bf16x8*)&fLo[((nt * 16 + ks) * 64 + l) * 8];
            acc = __builtin_amdgcn_mfma_f32_32x32x16_bf16(ah, bh, acc, 0, 0, 0);
            acc = __builtin_amdgcn_mfma_f32_32x32x16_bf16(al, bh, acc, 0, 0, 0);
            acc = __builtin_amdgcn_mfma_f32_32x32x16_bf16(ah, bl, acc, 0, 0, 0);
        }
        #pragma unroll
        for (int r = 0; r < 16; ++r) {
            int brow = mt * 32 + (r & 3) + 8 * (r >> 2) + 4 * (l >> 5);
            int bcol = nt * 32 + (l & 31);
            sim[brow][bcol] = acc[r];
        }
    }
    __syncthreads();
    // hardest positive: min over valid positive pairs (>=1 guaranteed)
    {
        int r = tid >> 2, q = tid & 3;
        const float INF = __int_as_float(0x7f800000);
        float m = INF;
        #pragma unroll
        for (int pp = 0; pp < 2; ++pp) {
            int p = q * 2 + pp;
            int j = pos_idx[r * P_DIM + p];
            int msk = pos_mask[r * P_DIM + p];
            float ps = sim[r][j];
            m = fminf(m, msk ? ps : INF);
        }
        m = fminf(m, __shfl_xor(m, 1));
        m = fminf(m, __shfl_xor(m, 2));
        if (q == 0) hp[r] = m;
    }
    __syncthreads();
    // hard negatives
    {
        int r = tid >> 2, q = tid & 3;
        float thr = hp[r] - 0.3f;
        float sum = 0.0f; int cnt = 0;
        #pragma unroll
        for (int nn = 0; nn < 8; ++nn) {
            int n = q * 8 + nn;
            int j = neg_idx[r * N_DIM + n];
            int msk = neg_mask[r * N_DIM + n];
            float ns = sim[r][j];
            if (msk && (ns > thr)) { cnt += 1; sum += softplusf(ns); }
        }
        sum += __shfl_xor(sum, 1); cnt += __shfl_xor(cnt, 1);
        sum += __shfl_xor(sum, 2); cnt += __shfl_xor(cnt, 2);
        if (q == 0) {
            float hn = (cnt > 0) ? (sum / (float)cnt) : 0.0f;
            contrib[r] = softplusf(-hp[r]) + hn;
        }
    }
    __syncthreads();
    if (tid == 0) {
        float s = 0.0f;
        for (int i = 0; i < 64; ++i) s += contrib[i];
        wsH[0] = s * (1.0f / 64.0f);
    }
}

// ---------------- Kernel B: logits = X @ V^T, K-split 4 ways across the block's waves ----------------
// Block = 256 thr (4 waves), tile = 32 columns of V. Wave w covers K in [w*64, w*64+64).
__global__ __launch_bounds__(256, 4)
void logits_kernel(const float* __restrict__ V, const unsigned short* __restrict__ wsA,
                   float* __restrict__ out) {
    __shared__ float red[4][2][16][65];        // [wave][mt][accreg][lane], 65 pad: conflict-free
    const int tid = threadIdx.x;
    const int w = tid >> 6, l = tid & 63;
    const int c0 = blockIdx.x * 32;
    const int c = c0 + (l & 31);
    const float* vbase = V + (size_t)c * D_DIM + w * 64 + 8 * (l >> 5);

    // issue all 8 V loads upfront (single latency exposure)
    float4 vld[8];
    #pragma unroll
    for (int ks = 0; ks < 4; ++ks) {
        vld[ks * 2]     = *(const float4*)(vbase + ks * 16);
        vld[ks * 2 + 1] = *(const float4*)(vbase + ks * 16 + 4);
    }
    // A fragments (pre-converted, L2-hot; 16B per lane per frag, coalesced)
    bf16x8 af0[4], af1[4];
    #pragma unroll
    for (int ks = 0; ks < 4; ++ks) {
        af0[ks] = *(const bf16x8*)(wsA + (((0 * 16) + (w * 4 + ks)) * 64 + l) * 8);
        af1[ks] = *(const bf16x8*)(wsA + (((1 * 16) + (w * 4 + ks)) * 64 + l) * 8);
    }
    f32x16 acc0, acc1;
    #pragma unroll
    for (int i = 0; i < 16; ++i) { acc0[i] = 0.0f; acc1[i] = 0.0f; }
    #pragma unroll
    for (int ks = 0; ks < 4; ++ks) {
        float4 r0 = vld[ks * 2], r1 = vld[ks * 2 + 1];
        float xs[8] = {r0.x, r0.y, r0.z, r0.w, r1.x, r1.y, r1.z, r1.w};
        bf16x8 vh;
        #pragma unroll
        for (int j = 0; j < 8; ++j) vh[j] = (short)bf16_rn(xs[j]);
        acc0 = __builtin_amdgcn_mfma_f32_32x32x16_bf16(af0[ks], vh, acc0, 0, 0, 0);
        acc1 = __builtin_amdgcn_mfma_f32_32x32x16_bf16(af1[ks], vh, acc1, 0, 0, 0);
    }
    // stash partials (conflict-free: fixed r, lanes -> consecutive dwords)
    #pragma unroll
    for (int r = 0; r < 16; ++r) {
        red[w][0][r][l] = acc0[r];
        red[w][1][r][l] = acc1[r];
    }
    __syncthreads();
    // reduce across the 4 K-slices and store logits
    const int g = tid >> 6;               // 0..3
    const int mt = g >> 1, rb = (g & 1) * 8;
    const int ll = tid & 63;
    #pragma unroll
    for (int rr = 0; rr < 8; ++rr) {
        int r = rb + rr;
        float v = (red[0][mt][r][ll] + red[1][mt][r][ll]) +
                  (red[2][mt][r][ll] + red[3][mt][r][ll]);
        int row = mt * 32 + (r & 3) + 8 * (r >> 2) + 4 * (ll >> 5);
        int col = c0 + (ll & 31);
        out[1 + (size_t)row * C_DIM + col] = v;
    }
}

// ---------------- Kernel C: per-segment exp-sums over the (L3-hot) logits ----------------
__global__ __launch_bounds__(256)
void rowsum_kernel(const float* __restrict__ out, float* __restrict__ wsQ) {
    const int row = blockIdx.x >> 3, seg = blockIdx.x & 7;
    const float* base = out + 1 + (size_t)row * C_DIM + seg * RS_LEN;
    float a0 = 0.f, a1 = 0.f, a2 = 0.f, a3 = 0.f;
    for (int j0 = threadIdx.x; j0 < RS_LEN; j0 += 1024) {
        int j1 = j0 + 256, j2 = j0 + 512, j3 = j0 + 768;
        a0 += expf(base[j0]);
        if (j1 < RS_LEN) a1 += expf(base[j1]);
        if (j2 < RS_LEN) a2 += expf(base[j2]);
        if (j3 < RS_LEN) a3 += expf(base[j3]);
    }
    float s = (a0 + a1) + (a2 + a3);
    #pragma unroll
    for (int m = 1; m <= 32; m <<= 1) s += __shfl_xor(s, m);
    __shared__ float ps[4];
    if ((threadIdx.x & 63) == 0) ps[threadIdx.x >> 6] = s;
    __syncthreads();
    if (threadIdx.x == 0) wsQ[blockIdx.x] = (ps[0] + ps[1]) + (ps[2] + ps[3]);
}

// ---------------- Kernel D: finalize loss ----------------
__global__ __launch_bounds__(64)
void final_kernel(float* __restrict__ out, const int* __restrict__ targets,
                  const float* __restrict__ wsQ, const float* __restrict__ wsH) {
    int b = threadIdx.x;
    float S = 0.0f;
    #pragma unroll
    for (int s = 0; s < 8; ++s) S += wsQ[b * 8 + s];
    float logZ = logf(S);
    int t = targets[b];
    float lb = logZ - out[1 + (size_t)b * C_DIM + t];
    #pragma unroll
    for (int m = 1; m <= 32; m <<= 1) lb += __shfl_xor(lb, m);
    if (b == 0) out[0] = lb * (1.0f / 64.0f) + wsH[0];
}

extern "C" void kernel_launch(void* const* d_in, const int* in_sizes, int n_in,
                              void* d_out, int out_size, void* d_ws, size_t ws_size,
                              hipStream_t stream) {
    (void)in_sizes; (void)n_in; (void)out_size; (void)ws_size;
    const float* X        = (const float*)d_in[0];
    const float* V        = (const float*)d_in[1];
    const int*   targets  = (const int*)d_in[2];
    const int*   pos_idx  = (const int*)d_in[3];
    const int*   pos_mask = (const int*)d_in[4];
    const int*   neg_idx  = (const int*)d_in[5];
    const int*   neg_mask = (const int*)d_in[6];
    float* out = (float*)d_out;
    float*          wsH = (float*)d_ws;                              // 1 float
    float*          wsQ = (float*)d_ws + 16;                         // 512 floats
    unsigned short* wsA = (unsigned short*)((char*)d_ws + 4096);     // 32 KB A-fragments

    hipLaunchKernelGGL(prep_kernel, dim3(1), dim3(256), 0, stream,
                       X, pos_idx, pos_mask, neg_idx, neg_mask, wsH, wsA);
    hipLaunchKernelGGL(logits_kernel, dim3(NTILE), dim3(256), 0, stream, V, wsA, out);
    hipLaunchKernelGGL(rowsum_kernel, dim3(B_DIM * RS_SEG), dim3(256), 0, stream, out, wsQ);
    hipLaunchKernelGGL(final_kernel, dim3(1), dim3(64), 0, stream, out, targets, wsQ, wsH);
}